// Round 3
// baseline (220.774 us; speedup 1.0000x reference)
//
#include <hip/hip_runtime.h>
#include <math.h>

// True problem dims (from reference constants, confirmed by npz sizes + NaN forensics):
// B=1, V=16, T=1, F=1 -> fv=16; N=12288 nodes, n=16 ch, K=9, ATT=128, NH=4, H=32, NA=4.
// All float tensors are FP32 on device. Attention seq per group = fv*NA = 64 tokens.
#define NFIELD 16
#define NNODE 12288
#define XSTRIDE (NNODE * 16)   // 196608 elems per field slice
#define NGRP 3072              // N / NA

typedef unsigned short u16;
typedef short short8 __attribute__((ext_vector_type(8)));
typedef float f32x4 __attribute__((ext_vector_type(4)));

// ws layout (bf16 elems): WqT[128][32] | WkvT[256][160] | WoutT[16][128] | W1T[32][32] | W2T[16][32]
#define WS_WQT   0
#define WS_WKVT  4096
#define WS_WOUTT 45056
#define WS_W1T   47104
#define WS_W2T   48128
#define WS_TOT   48640

__device__ __forceinline__ u16 f2b(float f) {   // f32 -> bf16 (RNE)
  unsigned u = __float_as_uint(f);
  return (u16)((u + 0x7FFFu + ((u >> 16) & 1u)) >> 16);
}
__device__ __forceinline__ float gelu_tanh(float v) {
  float u = v + 0.044715f * v * v * v;
  return 0.5f * v * (1.0f + tanhf(0.7978845608028654f * u));
}
// XOR swizzles: conflict-free ds_read_b128 on 256B/128B-stride rows (byte bits 4..6 ^ row&7)
__device__ __forceinline__ int swz256(int row, int cb) { return row * 256 + (cb ^ ((row & 7) << 4)); }
__device__ __forceinline__ int swz128(int row, int cb) { return row * 128 + (cb ^ ((row & 7) << 4)); }

__device__ __forceinline__ void redmax16(f32x4& v) {
  #pragma unroll
  for (int off = 1; off < 16; off <<= 1) {
    v[0] = fmaxf(v[0], __shfl_xor(v[0], off)); v[1] = fmaxf(v[1], __shfl_xor(v[1], off));
    v[2] = fmaxf(v[2], __shfl_xor(v[2], off)); v[3] = fmaxf(v[3], __shfl_xor(v[3], off));
  }
}
__device__ __forceinline__ void redsum16(f32x4& v) {
  #pragma unroll
  for (int off = 1; off < 16; off <<= 1) {
    v[0] += __shfl_xor(v[0], off); v[1] += __shfl_xor(v[1], off);
    v[2] += __shfl_xor(v[2], off); v[3] += __shfl_xor(v[3], off);
  }
}

// ---------- prep: f32 weights -> bf16, transposed [N][K] with zero K-padding ----------
__global__ void prep_weights(const float* __restrict__ Wq, const float* __restrict__ Wkv,
                             const float* __restrict__ Wout, const float* __restrict__ W1,
                             const float* __restrict__ W2, u16* __restrict__ ws) {
  int i = blockIdx.x * 256 + threadIdx.x;
  if (i >= WS_TOT) return;
  int j = i;
  if (j < 4096) { int n = j >> 5, k = j & 31; ws[WS_WQT + j] = f2b(k < 16 ? Wq[k * 128 + n] : 0.f); return; }
  j -= 4096;
  if (j < 40960) { int n = j / 160, k = j % 160; ws[WS_WKVT + j] = f2b(k < 144 ? Wkv[k * 256 + n] : 0.f); return; }
  j -= 40960;
  if (j < 2048) { int n = j >> 7, k = j & 127; ws[WS_WOUTT + j] = f2b(Wout[k * 16 + n]); return; }
  j -= 2048;
  if (j < 1024) { int n = j >> 5, k = j & 31; ws[WS_W1T + j] = f2b(k < 16 ? W1[k * 32 + n] : 0.f); return; }
  j -= 1024;
  { int n = j >> 5, k = j & 31; ws[WS_W2T + j] = f2b(W2[k * 16 + n]); }
}

// ---------- main fused kernel: one block per attention group ----------
__global__ __launch_bounds__(256)
void mfa_main(const float* __restrict__ x, const int* __restrict__ adjc,
              const float* __restrict__ ln1s, const float* __restrict__ ln1b,
              const float* __restrict__ bkv, const float* __restrict__ bout,
              const float* __restrict__ gamma, const float* __restrict__ ln2s,
              const float* __restrict__ ln2b, const float* __restrict__ b1,
              const float* __restrict__ b2, const float* __restrict__ gmlp,
              const u16* __restrict__ ws, float* __restrict__ y)
{
  // LDS arena, 63488 B -> 2 blocks/CU
  __shared__ __align__(16) unsigned char smem[63488];
  u16*  kvnp = (u16*)(smem);            // R1: kvn[64][40] -> p[64][72] -> hid[64][40]
  u16*  qnp  = (u16*)(smem + 9216);     // R2: qn/h [64][40] (cols 16..39 stay zero = K-pad)
  char* qpp  = (char*)(smem + 14336);   // R3: qp -> o, [64][128] bf16, swz256
  char* kkp  = (char*)(smem + 30720);   // R4: k [64][128] bf16 swz256 -> xo f32 [64][16]
  char* vtp  = (char*)(smem + 47104);   // R5: vT [128][64] bf16 swz128
  float* xop = (float*)(smem + 30720);

  const int t = threadIdx.x, g = blockIdx.x;
  const int l = t & 63, w = t >> 6;
  const int lrow = l & 15, kgrp = l >> 4, k0 = kgrp * 8;
  const int half = t & 1;

  const u16* WqT   = ws + WS_WQT;
  const u16* WkvT  = ws + WS_WKVT;
  const u16* WoutT = ws + WS_WOUTT;
  const u16* W1T   = ws + WS_W1T;
  const u16* W2T   = ws + WS_W2T;
  const f32x4 z4 = {0.f, 0.f, 0.f, 0.f};

  // ln1 params for this thread's half (used by P1 + all gather chunks)
  float lns[8], lnb[8];
  #pragma unroll
  for (int j = 0; j < 8; ++j) { lns[j] = ln1s[half * 8 + j]; lnb[j] = ln1b[half * 8 + j]; }

  // ---- P0: zero qn K-pad (cols 16..39) ----
  for (int i = t; i < 768; i += 256) {
    int row = i / 12, cw = i % 12;
    *(unsigned*)((char*)qnp + row * 80 + 32 + cw * 4) = 0u;
  }
  // ---- P1: LN1 of the 64 own tokens -> qn cols 0..15 (bf16) ----
  if (t < 128) {
    int tau = t >> 1;
    int v = tau >> 2, node = g * 4 + (tau & 3);
    const float4* xp = (const float4*)(x + v * XSTRIDE + node * 16 + half * 8);
    float4 p0 = xp[0], p1 = xp[1];
    float va[8] = {p0.x, p0.y, p0.z, p0.w, p1.x, p1.y, p1.z, p1.w};
    float s = 0.f, ss = 0.f;
    #pragma unroll
    for (int j = 0; j < 8; ++j) { s += va[j]; ss += va[j] * va[j]; }
    s += __shfl_xor(s, 1); ss += __shfl_xor(ss, 1);
    float mean = s * 0.0625f, var = ss * 0.0625f - mean * mean;
    float rs = rsqrtf(var + 1e-5f);
    u16* dst = qnp + tau * 40 + half * 8;
    short8 o;
    #pragma unroll
    for (int j = 0; j < 8; ++j) o[j] = (short)f2b((va[j] - mean) * rs * lns[j] + lnb[j]);
    *(short8*)dst = o;
  }
  __syncthreads();

  // ---- P2: q-proj MFMA: qp[64][128] = qn @ WqT  (wave w -> N-tiles 2w,2w+1) ----
  {
    short8 a[4];
    #pragma unroll
    for (int mt = 0; mt < 4; ++mt) a[mt] = *(const short8*)(qnp + (mt * 16 + lrow) * 40 + k0);
    #pragma unroll
    for (int ntl = 0; ntl < 2; ++ntl) {
      int n = (w * 2 + ntl) * 16 + lrow;
      short8 b = *(const short8*)(WqT + n * 32 + k0);
      #pragma unroll
      for (int mt = 0; mt < 4; ++mt) {
        f32x4 acc = __builtin_amdgcn_mfma_f32_16x16x32_bf16(a[mt], b, z4, 0, 0, 0);
        #pragma unroll
        for (int r = 0; r < 4; ++r)
          *(u16*)(qpp + swz256(mt * 16 + kgrp * 4 + r, n * 2)) = f2b(acc[r]);
      }
    }
  }

  // ---- P3: kv-proj: [64][144] @ WkvT -> k[64][128], vT[128][64]; K chunked 5x32 ----
  {
    f32x4 acc[4][4];
    #pragma unroll
    for (int mt = 0; mt < 4; ++mt)
      #pragma unroll
      for (int q = 0; q < 4; ++q) acc[mt][q] = z4;

    for (int kc = 0; kc < 5; ++kc) {
      // gather + LN of neighbors {2kc, 2kc+1} into kvn[64][40]
      {
        int job = t >> 1;
        int tau = job & 63, nbl = job >> 6;
        int nbr = kc * 2 + nbl;
        u16* dst = kvnp + tau * 40 + nbl * 16 + half * 8;
        if (nbr < 9) {
          int v = tau >> 2, node = g * 4 + (tau & 3);
          int an = adjc[node * 9 + nbr];
          const float4* xp = (const float4*)(x + v * XSTRIDE + an * 16 + half * 8);
          float4 p0 = xp[0], p1 = xp[1];
          float va[8] = {p0.x, p0.y, p0.z, p0.w, p1.x, p1.y, p1.z, p1.w};
          float s = 0.f, ss = 0.f;
          #pragma unroll
          for (int j = 0; j < 8; ++j) { s += va[j]; ss += va[j] * va[j]; }
          s += __shfl_xor(s, 1); ss += __shfl_xor(ss, 1);
          float mean = s * 0.0625f, var = ss * 0.0625f - mean * mean;
          float rs = rsqrtf(var + 1e-5f);
          short8 o;
          #pragma unroll
          for (int j = 0; j < 8; ++j) o[j] = (short)f2b((va[j] - mean) * rs * lns[j] + lnb[j]);
          *(short8*)dst = o;
        } else {
          short8 zz = {0, 0, 0, 0, 0, 0, 0, 0};
          *(short8*)dst = zz;
        }
      }
      __syncthreads();
      short8 a[4];
      #pragma unroll
      for (int mt = 0; mt < 4; ++mt) a[mt] = *(const short8*)(kvnp + (mt * 16 + lrow) * 40 + k0);
      #pragma unroll
      for (int q = 0; q < 4; ++q) {
        int n = (w * 4 + q) * 16 + lrow;
        short8 b = *(const short8*)(WkvT + n * 160 + kc * 32 + k0);
        #pragma unroll
        for (int mt = 0; mt < 4; ++mt)
          acc[mt][q] = __builtin_amdgcn_mfma_f32_16x16x32_bf16(a[mt], b, acc[mt][q], 0, 0, 0);
      }
      __syncthreads();
    }
    // bias + write k / vT
    #pragma unroll
    for (int q = 0; q < 4; ++q) {
      int ch = (w * 4 + q) * 16 + lrow;
      float bk = bkv[ch];
      #pragma unroll
      for (int mt = 0; mt < 4; ++mt)
        #pragma unroll
        for (int r = 0; r < 4; ++r) {
          int tau = mt * 16 + kgrp * 4 + r;
          u16 v16 = f2b(acc[mt][q][r] + bk);
          if (ch < 128) *(u16*)(kkp + swz256(tau, ch * 2)) = v16;
          else          *(u16*)(vtp + swz128(ch - 128, tau * 2)) = v16;
        }
    }
  }
  __syncthreads();

  // ---- P4/P5: per-head QK -> softmax -> PV. M-split: wave w owns rows [16w,16w+16).
  // p (shared, one head at a time) lives in R1; o overwrites qp column-slice head*32..+32.
  const float SC = 0.17677669529663687f;  // 1/sqrt(32)
  for (int h = 0; h < 4; ++h) {
    short8 aq = *(const short8*)(qpp + swz256(w * 16 + lrow, (h * 32 + k0) * 2));
    f32x4 s4[4];
    #pragma unroll
    for (int nt = 0; nt < 4; ++nt) {
      short8 bk = *(const short8*)(kkp + swz256(nt * 16 + lrow, (h * 32 + k0) * 2));
      s4[nt] = __builtin_amdgcn_mfma_f32_16x16x32_bf16(aq, bk, z4, 0, 0, 0);
    }
    f32x4 m4;
    #pragma unroll
    for (int c = 0; c < 4; ++c)
      m4[c] = fmaxf(fmaxf(s4[0][c], s4[1][c]), fmaxf(s4[2][c], s4[3][c]));
    redmax16(m4);
    f32x4 e[4]; f32x4 esum = z4;
    #pragma unroll
    for (int nt = 0; nt < 4; ++nt) {
      #pragma unroll
      for (int c = 0; c < 4; ++c) e[nt][c] = __expf((s4[nt][c] - m4[c]) * SC);
      esum += e[nt];
    }
    redsum16(esum);
    f32x4 inv;
    #pragma unroll
    for (int c = 0; c < 4; ++c) inv[c] = 1.0f / esum[c];
    #pragma unroll
    for (int nt = 0; nt < 4; ++nt)
      #pragma unroll
      for (int r = 0; r < 4; ++r)
        *((u16*)((char*)kvnp + (w * 16 + kgrp * 4 + r) * 144) + nt * 16 + lrow) = f2b(e[nt][r] * inv[r]);
    __syncthreads();
    // PV
    f32x4 oacc[2] = {z4, z4};
    #pragma unroll
    for (int kc = 0; kc < 2; ++kc) {
      short8 ap = *(const short8*)((char*)kvnp + (w * 16 + lrow) * 144 + (kc * 32 + k0) * 2);
      #pragma unroll
      for (int nt = 0; nt < 2; ++nt) {
        short8 bv = *(const short8*)(vtp + swz128(h * 32 + nt * 16 + lrow, (kc * 32 + k0) * 2));
        oacc[nt] = __builtin_amdgcn_mfma_f32_16x16x32_bf16(ap, bv, oacc[nt], 0, 0, 0);
      }
    }
    #pragma unroll
    for (int nt = 0; nt < 2; ++nt)
      #pragma unroll
      for (int r = 0; r < 4; ++r)
        *(u16*)(qpp + swz256(w * 16 + kgrp * 4 + r, (h * 32 + nt * 16 + lrow) * 2)) = f2b(oacc[nt][r]);
    __syncthreads();
  }

  // ---- P6: out-proj (wave w -> its 16 rows) + gamma residual + LN2 ----
  {
    f32x4 acc = z4;
    #pragma unroll
    for (int kc = 0; kc < 4; ++kc) {
      short8 ao = *(const short8*)(qpp + swz256(w * 16 + lrow, (kc * 32 + k0) * 2));
      short8 bo = *(const short8*)(WoutT + lrow * 128 + kc * 32 + k0);
      acc = __builtin_amdgcn_mfma_f32_16x16x32_bf16(ao, bo, acc, 0, 0, 0);
    }
    int ch = lrow;
    float gmm = gamma[ch], bo_ = bout[ch], l2s = ln2s[ch], l2b = ln2b[ch];
    float xov[4];
    #pragma unroll
    for (int r = 0; r < 4; ++r) {
      int tau = w * 16 + kgrp * 4 + r;
      int v = tau >> 2, node = g * 4 + (tau & 3);
      float xv = x[v * XSTRIDE + node * 16 + ch];
      xov[r] = xv + gmm * (acc[r] + bo_);
    }
    f32x4 sv = {xov[0], xov[1], xov[2], xov[3]};
    f32x4 qv = sv * sv;
    redsum16(sv); redsum16(qv);
    #pragma unroll
    for (int r = 0; r < 4; ++r) {
      int tau = w * 16 + kgrp * 4 + r;
      float mean = sv[r] * 0.0625f, var = qv[r] * 0.0625f - mean * mean;
      float rs = rsqrtf(var + 1e-5f);
      xop[tau * 16 + ch] = xov[r];
      qnp[tau * 40 + ch] = f2b((xov[r] - mean) * rs * l2s + l2b);
    }
  }
  __syncthreads();

  // ---- P7: MLP hidden 16->32 + gelu (hid into R1) ----
  {
    short8 ah = *(const short8*)(qnp + (w * 16 + lrow) * 40 + k0);
    #pragma unroll
    for (int nt = 0; nt < 2; ++nt) {
      int n = nt * 16 + lrow;
      short8 b = *(const short8*)(W1T + n * 32 + k0);
      f32x4 hacc = __builtin_amdgcn_mfma_f32_16x16x32_bf16(ah, b, z4, 0, 0, 0);
      float b1v = b1[n];
      #pragma unroll
      for (int r = 0; r < 4; ++r) {
        int tau = w * 16 + kgrp * 4 + r;
        kvnp[tau * 40 + n] = f2b(gelu_tanh(hacc[r] + b1v));
      }
    }
  }
  __syncthreads();

  // ---- P8: MLP out 32->16 + gamma_mlp residual -> y ----
  {
    short8 ahid = *(const short8*)(kvnp + (w * 16 + lrow) * 40 + k0);
    short8 b = *(const short8*)(W2T + lrow * 32 + k0);
    f32x4 macc = __builtin_amdgcn_mfma_f32_16x16x32_bf16(ahid, b, z4, 0, 0, 0);
    float b2v = b2[lrow], gm2 = gmlp[lrow];
    #pragma unroll
    for (int r = 0; r < 4; ++r) {
      int tau = w * 16 + kgrp * 4 + r;
      int v = tau >> 2, node = g * 4 + (tau & 3);
      y[v * XSTRIDE + node * 16 + lrow] = xop[tau * 16 + lrow] + gm2 * (macc[r] + b2v);
    }
  }
}

extern "C" void kernel_launch(void* const* d_in, const int* in_sizes, int n_in,
                              void* d_out, int out_size, void* d_ws, size_t ws_size,
                              hipStream_t stream) {
  const float* x    = (const float*)d_in[0];
  const int*   adjc = (const int*)  d_in[1];
  const float* ln1s = (const float*)d_in[2];
  const float* ln1b = (const float*)d_in[3];
  const float* Wq   = (const float*)d_in[4];
  const float* Wkv  = (const float*)d_in[5];
  const float* bkv  = (const float*)d_in[6];
  const float* Wout = (const float*)d_in[7];
  const float* bout = (const float*)d_in[8];
  const float* gam  = (const float*)d_in[9];
  const float* ln2s = (const float*)d_in[10];
  const float* ln2b = (const float*)d_in[11];
  const float* W1   = (const float*)d_in[12];
  const float* b1   = (const float*)d_in[13];
  const float* W2   = (const float*)d_in[14];
  const float* b2   = (const float*)d_in[15];
  const float* gmlp = (const float*)d_in[16];
  float* y = (float*)d_out;
  u16* ws = (u16*)d_ws;

  prep_weights<<<(WS_TOT + 255) / 256, 256, 0, stream>>>(Wq, Wkv, Wout, W1, W2, ws);
  mfa_main<<<NGRP, 256, 0, stream>>>(x, adjc, ln1s, ln1b, bkv, bout, gam,
                                     ln2s, ln2b, b1, b2, gmlp, ws, y);
}

// Round 4
// 198.918 us; speedup vs baseline: 1.1099x; 1.1099x over previous
//
#include <hip/hip_runtime.h>
#include <math.h>

// Dims: B=1,V=16,T=1,F=1 -> fv=16; N=12288, n=16, K=9, ATT=128, NH=4, H=32, NA=4.
// All float tensors FP32 on device. 64 tokens (16 fields x 4 nodes) per attention group.
#define NNODE 12288
#define XSTRIDE 196608          // elems per field slice (12288*16)
#define NGRP 3072               // N/NA
#define XT_ELEMS 3145728        // 12288*256 bf16: LN1'd tokens, [node][v][ch]
// weight offsets (u16 elems) relative to wbase = ws + XT_ELEMS
#define WS_WQT   0              // WqT[128][32]  (K-pad 16->32)
#define WS_WKVT  4096           // WkvT[256][160] (K-pad 144->160)
#define WS_WOUTT 45056          // WoutT[16][128]
#define WS_W1T   47104          // W1T[32][32]   (K-pad 16->32)
#define WS_W2T   48128          // W2T[16][32]
#define WS_WTOT  48640
#define WS_BYTES ((size_t)(XT_ELEMS + WS_WTOT) * 2)

// LDS arena (57344 B -> 2 blocks/CU, static <64KB)
#define PSLOT_OFF 16384         // + w*2048 ; stage[64][168]@0 -> k[64][128]@0 + pslots
#define QP_OFF    24576         // qp[64][128] swz256 ; O at QP_OFF + w*4096 (post-S)
#define VT_OFF    40960         // vT[128][64] swz128
#define LDS_TOTAL 57344

typedef unsigned short u16;
typedef short short8 __attribute__((ext_vector_type(8)));
typedef float f32x4 __attribute__((ext_vector_type(4)));

__device__ __forceinline__ u16 f2b(float f) {          // f32->bf16 RNE (prep path)
  unsigned u = __float_as_uint(f);
  return (u16)((u + 0x7FFFu + ((u >> 16) & 1u)) >> 16);
}
__device__ __forceinline__ u16 rtz(float f) {          // f32->bf16 RTZ (1 op; gamma=1e-6 damps error)
  return (u16)(__float_as_uint(f) >> 16);
}
__device__ __forceinline__ float gelu_tanh(float v) {
  float u = v + 0.044715f * v * v * v;
  return 0.5f * v * (1.0f + tanhf(0.7978845608028654f * u));
}
// in-order DS pipe + compile-time fence: wave-local LDS write->read transitions
#define DS_FENCE() do { asm volatile("s_waitcnt lgkmcnt(0)" ::: "memory"); \
                        __builtin_amdgcn_sched_barrier(0); } while (0)

__device__ __forceinline__ void redmax16(f32x4& v) {
  #pragma unroll
  for (int off = 1; off <= 8; off <<= 1) {
    v[0] = fmaxf(v[0], __shfl_xor(v[0], off)); v[1] = fmaxf(v[1], __shfl_xor(v[1], off));
    v[2] = fmaxf(v[2], __shfl_xor(v[2], off)); v[3] = fmaxf(v[3], __shfl_xor(v[3], off));
  }
}
__device__ __forceinline__ void redsum16(f32x4& v) {
  #pragma unroll
  for (int off = 1; off <= 8; off <<= 1) {
    v[0] += __shfl_xor(v[0], off); v[1] += __shfl_xor(v[1], off);
    v[2] += __shfl_xor(v[2], off); v[3] += __shfl_xor(v[3], off);
  }
}

// ---------- prep: f32 weights -> bf16 transposed [N][K], zero K-pad ----------
__global__ void prep_weights(const float* __restrict__ Wq, const float* __restrict__ Wkv,
                             const float* __restrict__ Wout, const float* __restrict__ W1,
                             const float* __restrict__ W2, u16* __restrict__ wbase) {
  int i = blockIdx.x * 256 + threadIdx.x;
  if (i >= WS_WTOT) return;
  int j = i;
  if (j < 4096)  { int n = j >> 5, k = j & 31;   wbase[WS_WQT   + j] = f2b(k < 16  ? Wq[k * 128 + n]  : 0.f); return; }
  j -= 4096;
  if (j < 40960) { int n = j / 160, k = j % 160; wbase[WS_WKVT  + j] = f2b(k < 144 ? Wkv[k * 256 + n] : 0.f); return; }
  j -= 40960;
  if (j < 2048)  { int n = j >> 7, k = j & 127;  wbase[WS_WOUTT + j] = f2b(Wout[k * 16 + n]); return; }
  j -= 2048;
  if (j < 1024)  { int n = j >> 5, k = j & 31;   wbase[WS_W1T   + j] = f2b(k < 16 ? W1[k * 32 + n] : 0.f); return; }
  j -= 1024;
  { int n = j >> 5, k = j & 31; wbase[WS_W2T + j] = f2b(W2[k * 16 + n]); }
}

// ---------- ln1x: LN1 once per token -> xt[node][v][ch] bf16 ----------
__global__ __launch_bounds__(256)
void ln1x_kernel(const float* __restrict__ x, const float* __restrict__ ln1s,
                 const float* __restrict__ ln1b, u16* __restrict__ xt) {
  int tid = blockIdx.x * 256 + threadIdx.x;   // 768 blocks * 256 = 196608 tokens
  int node = tid >> 4, v = tid & 15;
  const float4* xp = (const float4*)(x + (size_t)v * XSTRIDE + node * 16);
  float4 p0 = xp[0], p1 = xp[1], p2 = xp[2], p3 = xp[3];
  float va[16] = {p0.x,p0.y,p0.z,p0.w, p1.x,p1.y,p1.z,p1.w,
                  p2.x,p2.y,p2.z,p2.w, p3.x,p3.y,p3.z,p3.w};
  float s = 0.f, ss = 0.f;
  #pragma unroll
  for (int j = 0; j < 16; ++j) { s += va[j]; ss += va[j] * va[j]; }
  float mean = s * 0.0625f, var = ss * 0.0625f - mean * mean, rs = rsqrtf(var + 1e-5f);
  short8 o0, o1;
  #pragma unroll
  for (int j = 0; j < 8; ++j) {
    o0[j] = (short)f2b((va[j]     - mean) * rs * ln1s[j]     + ln1b[j]);
    o1[j] = (short)f2b((va[j + 8] - mean) * rs * ln1s[j + 8] + ln1b[j + 8]);
  }
  short8* dst = (short8*)(xt + node * 256 + v * 16);
  dst[0] = o0; dst[1] = o1;
}

// ---------- main fused kernel: one block per attention group ----------
__global__ __launch_bounds__(256)
void mfa_main(const float* __restrict__ x, const int* __restrict__ adjc,
              const float* __restrict__ bkv, const float* __restrict__ bout,
              const float* __restrict__ gamma, const float* __restrict__ ln2s,
              const float* __restrict__ ln2b, const float* __restrict__ b1,
              const float* __restrict__ b2, const float* __restrict__ gmlp,
              const u16* __restrict__ ws, float* __restrict__ y)
{
  __shared__ __align__(16) unsigned char smem[LDS_TOTAL];
  const int t = threadIdx.x, g = blockIdx.x;
  const int w = t >> 6, l = t & 63;
  const int lrow = l & 15, kgrp = l >> 4, k0 = kgrp * 8;

  char* kbuf  = (char*)smem;                          // post-stage: k[64][128] swz256
  char* pslot = (char*)(smem + PSLOT_OFF + w * 2048); // wave-local P/h/hid
  char* qpb   = (char*)(smem + QP_OFF);               // qp[64][128] swz256
  char* obuf  = (char*)(smem + QP_OFF + w * 4096);    // wave-local O (overwrites own qp rows)
  char* vtb   = (char*)(smem + VT_OFF);               // vT[128][64] swz128

  const u16* xt    = ws;
  const u16* wbase = ws + XT_ELEMS;
  const u16* WqT   = wbase + WS_WQT;
  const u16* WkvT  = wbase + WS_WKVT;
  const u16* WoutT = wbase + WS_WOUTT;
  const u16* W1T   = wbase + WS_W1T;
  const u16* W2T   = wbase + WS_W2T;
  const f32x4 z4 = {0.f, 0.f, 0.f, 0.f};
  const short8 z8 = {0, 0, 0, 0, 0, 0, 0, 0};

  // ======== Phase A: issue all global loads early; stage kvn; qproj ========
  float xres[4];
  #pragma unroll
  for (int r = 0; r < 4; ++r) {
    int tau = w * 16 + kgrp * 4 + r;
    xres[r] = x[(size_t)(tau >> 2) * XSTRIDE + (g * 4 + (tau & 3)) * 16 + lrow];
  }
  float g_gam = gamma[lrow], g_bout = bout[lrow], g_l2s = ln2s[lrow], g_l2b = ln2b[lrow];
  float g_b2 = b2[lrow], g_gm2 = gmlp[lrow], g_b1a = b1[lrow], g_b1b = b1[16 + lrow];
  float g_bkv[4];
  #pragma unroll
  for (int q = 0; q < 4; ++q) g_bkv[q] = bkv[(w * 4 + q) * 16 + lrow];

  // qproj A fragments direct from xt (kgrp>=2 are K-pad zeros)
  short8 qa[4];
  #pragma unroll
  for (int mt = 0; mt < 4; ++mt) {
    if (kgrp < 2) {
      int tau = mt * 16 + lrow;
      qa[mt] = *(const short8*)(xt + (g * 4 + (tau & 3)) * 256 + (tau >> 2) * 16 + k0);
    } else qa[mt] = z8;
  }
  short8 qb[2];
  #pragma unroll
  for (int ntl = 0; ntl < 2; ++ntl) {
    int n = (w * 2 + ntl) * 16 + lrow;
    qb[ntl] = *(const short8*)(WqT + n * 32 + k0);
  }

  // kvn staging: 1280 jobs (1152 data slabs + 128 zero-pad), 5 passes
  int   srow[5], scolb[5]; bool sz[5]; int an[5]; short8 sv[5];
  #pragma unroll
  for (int p = 0; p < 5; ++p) {
    int j = p * 256 + t, s = j >> 5, half = j & 1;
    if (s < 36) {
      int ni = s / 9, k = s % 9, v = (j & 31) >> 1;
      an[p] = adjc[g * 36 + s];
      srow[p] = v * 4 + ni; scolb[p] = k * 32 + half * 16; sz[p] = false;
    } else {
      srow[p] = (s - 36) * 16 + ((j & 31) >> 1); scolb[p] = 288 + half * 16; sz[p] = true;
      an[p] = 0;
    }
  }
  #pragma unroll
  for (int p = 0; p < 5; ++p) {
    if (!sz[p]) {
      int j = p * 256 + t, v = (j & 31) >> 1, half = j & 1;
      sv[p] = *(const short8*)(xt + an[p] * 256 + v * 16 + half * 8);
    } else sv[p] = z8;
  }
  #pragma unroll
  for (int p = 0; p < 5; ++p)
    *(short8*)((char*)smem + srow[p] * 336 + scolb[p]) = sv[p];   // stage [64][168]

  // qproj MFMAs -> qp (swz256)
  #pragma unroll
  for (int ntl = 0; ntl < 2; ++ntl) {
    int n = (w * 2 + ntl) * 16 + lrow;
    #pragma unroll
    for (int mt = 0; mt < 4; ++mt) {
      f32x4 c = __builtin_amdgcn_mfma_f32_16x16x32_bf16(qa[mt], qb[ntl], z4, 0, 0, 0);
      #pragma unroll
      for (int r = 0; r < 4; ++r) {
        int row = mt * 16 + kgrp * 4 + r;
        *(u16*)(qpb + row * 256 + ((2 * n) ^ ((row & 7) << 4))) = rtz(c[r]);
      }
    }
  }
  __syncthreads();   // bar1: stage + qp visible

  // ======== Phase B: kv-proj [64][160] @ WkvT -> k, vT ========
  f32x4 acc[4][4];
  #pragma unroll
  for (int mt = 0; mt < 4; ++mt)
    #pragma unroll
    for (int q = 0; q < 4; ++q) acc[mt][q] = z4;
  #pragma unroll
  for (int kc = 0; kc < 5; ++kc) {
    short8 a[4], b[4];
    #pragma unroll
    for (int mt = 0; mt < 4; ++mt)
      a[mt] = *(const short8*)((char*)smem + (mt * 16 + lrow) * 336 + kc * 64 + kgrp * 16);
    #pragma unroll
    for (int q = 0; q < 4; ++q) {
      int n = (w * 4 + q) * 16 + lrow;
      b[q] = *(const short8*)(WkvT + n * 160 + kc * 32 + k0);
    }
    #pragma unroll
    for (int q = 0; q < 4; ++q)
      #pragma unroll
      for (int mt = 0; mt < 4; ++mt)
        acc[mt][q] = __builtin_amdgcn_mfma_f32_16x16x32_bf16(a[mt], b[q], acc[mt][q], 0, 0, 0);
  }
  __syncthreads();   // bar1.5: all stage reads done before k overwrites region
  #pragma unroll
  for (int q = 0; q < 4; ++q) {
    int ch = (w * 4 + q) * 16 + lrow;
    float bk = g_bkv[q];
    #pragma unroll
    for (int mt = 0; mt < 4; ++mt)
      #pragma unroll
      for (int r = 0; r < 4; ++r) {
        int tau = mt * 16 + kgrp * 4 + r;
        u16 val = rtz(acc[mt][q][r] + bk);
        if (ch < 128) *(u16*)(kbuf + tau * 256 + ((2 * ch) ^ ((tau & 7) << 4))) = val;
        else { int vc = ch - 128; *(u16*)(vtb + vc * 128 + ((2 * tau) ^ ((vc & 7) << 4))) = val; }
      }
  }
  __syncthreads();   // bar2: k/vT visible

  // ======== Phase C: per-head QK -> softmax -> PV (zero barriers, wave-local) ========
  const float SC = 0.17677669529663687f;   // 1/sqrt(32)
  f32x4 o[4][2]; f32x4 invs[4];
  #pragma unroll
  for (int h = 0; h < 4; ++h) { o[h][0] = z4; o[h][1] = z4; }
  #pragma unroll
  for (int h = 0; h < 4; ++h) {
    int arow = w * 16 + lrow;
    short8 aq = *(const short8*)(qpb + arow * 256 + ((64 * h + 16 * kgrp) ^ ((arow & 7) << 4)));
    f32x4 s4[4];
    #pragma unroll
    for (int nt = 0; nt < 4; ++nt) {
      int krow = nt * 16 + lrow;
      short8 bk = *(const short8*)(kbuf + krow * 256 + ((64 * h + 16 * kgrp) ^ ((krow & 7) << 4)));
      s4[nt] = __builtin_amdgcn_mfma_f32_16x16x32_bf16(aq, bk, z4, 0, 0, 0);
    }
    f32x4 m4;
    #pragma unroll
    for (int c = 0; c < 4; ++c)
      m4[c] = fmaxf(fmaxf(s4[0][c], s4[1][c]), fmaxf(s4[2][c], s4[3][c]));
    redmax16(m4);
    f32x4 esum = z4;
    #pragma unroll
    for (int nt = 0; nt < 4; ++nt) {
      #pragma unroll
      for (int c = 0; c < 4; ++c) s4[nt][c] = __expf((s4[nt][c] - m4[c]) * SC);
      esum += s4[nt];
    }
    redsum16(esum);
    #pragma unroll
    for (int c = 0; c < 4; ++c) invs[h][c] = 1.0f / esum[c];
    // write unnormalized P to wave-local pslot [16][64] bf16 swz
    #pragma unroll
    for (int nt = 0; nt < 4; ++nt)
      #pragma unroll
      for (int r = 0; r < 4; ++r) {
        int row = kgrp * 4 + r;
        *(u16*)(pslot + row * 128 + ((2 * (nt * 16 + lrow)) ^ ((row & 7) << 4))) = rtz(s4[nt][r]);
      }
    DS_FENCE();
    #pragma unroll
    for (int kc = 0; kc < 2; ++kc) {
      short8 ap = *(const short8*)(pslot + lrow * 128 + ((64 * kc + 16 * kgrp) ^ ((lrow & 7) << 4)));
      #pragma unroll
      for (int nt = 0; nt < 2; ++nt) {
        int vr = h * 32 + nt * 16 + lrow;
        short8 bv = *(const short8*)(vtb + vr * 128 + ((64 * kc + 16 * kgrp) ^ ((vr & 7) << 4)));
        o[h][nt] = __builtin_amdgcn_mfma_f32_16x16x32_bf16(ap, bv, o[h][nt], 0, 0, 0);
      }
    }
  }
  // O (normalized) -> wave-local rows of qp region (qp reads for this wave are done)
  #pragma unroll
  for (int h = 0; h < 4; ++h)
    #pragma unroll
    for (int nt = 0; nt < 2; ++nt)
      #pragma unroll
      for (int r = 0; r < 4; ++r) {
        int row = kgrp * 4 + r, och = h * 32 + nt * 16 + lrow;
        *(u16*)(obuf + row * 256 + ((2 * och) ^ ((row & 7) << 4))) = rtz(o[h][nt][r] * invs[h][r]);
      }
  DS_FENCE();

  // ======== Phase D: out-proj + LN2 + MLP (wave-local, no barriers) ========
  f32x4 oc = z4;
  #pragma unroll
  for (int kc = 0; kc < 4; ++kc) {
    short8 ao = *(const short8*)(obuf + lrow * 256 + ((64 * kc + 16 * kgrp) ^ ((lrow & 7) << 4)));
    short8 bo = *(const short8*)(WoutT + lrow * 128 + kc * 32 + k0);
    oc = __builtin_amdgcn_mfma_f32_16x16x32_bf16(ao, bo, oc, 0, 0, 0);
  }
  float xov[4]; f32x4 sv_, qv_;
  #pragma unroll
  for (int r = 0; r < 4; ++r) {
    xov[r] = xres[r] + g_gam * (oc[r] + g_bout);
    sv_[r] = xov[r]; qv_[r] = xov[r] * xov[r];
  }
  redsum16(sv_); redsum16(qv_);
  #pragma unroll
  for (int r = 0; r < 4; ++r) {
    int row = kgrp * 4 + r;
    float mean = sv_[r] * 0.0625f, var = qv_[r] * 0.0625f - mean * mean;
    float rs = rsqrtf(var + 1e-5f);
    *(u16*)(pslot + row * 80 + 2 * lrow)      = rtz((xov[r] - mean) * rs * g_l2s + g_l2b);
    *(u16*)(pslot + row * 80 + 32 + 2 * lrow) = 0;   // K-pad cols 16..31
  }
  DS_FENCE();
  // mlp1: h[16][32] @ W1T -> gelu -> hid (overwrites h, in-order)
  short8 ah = *(const short8*)(pslot + lrow * 80 + kgrp * 16);
  u16 hidv[8];
  #pragma unroll
  for (int nt = 0; nt < 2; ++nt) {
    int n = nt * 16 + lrow;
    short8 bf = *(const short8*)(W1T + n * 32 + k0);
    f32x4 hc = __builtin_amdgcn_mfma_f32_16x16x32_bf16(ah, bf, z4, 0, 0, 0);
    float bb = nt ? g_b1b : g_b1a;
    #pragma unroll
    for (int r = 0; r < 4; ++r) hidv[nt * 4 + r] = rtz(gelu_tanh(hc[r] + bb));
  }
  #pragma unroll
  for (int nt = 0; nt < 2; ++nt)
    #pragma unroll
    for (int r = 0; r < 4; ++r) {
      int row = kgrp * 4 + r;
      *(u16*)(pslot + row * 80 + 2 * (nt * 16 + lrow)) = hidv[nt * 4 + r];
    }
  DS_FENCE();
  // mlp2: hid[16][32] @ W2T + gamma_mlp residual -> y
  short8 ahid = *(const short8*)(pslot + lrow * 80 + kgrp * 16);
  short8 b2f  = *(const short8*)(W2T + lrow * 32 + k0);
  f32x4 mc = __builtin_amdgcn_mfma_f32_16x16x32_bf16(ahid, b2f, z4, 0, 0, 0);
  #pragma unroll
  for (int r = 0; r < 4; ++r) {
    int tau = w * 16 + kgrp * 4 + r;
    y[(size_t)(tau >> 2) * XSTRIDE + (g * 4 + (tau & 3)) * 16 + lrow] =
        xov[r] + g_gm2 * (mc[r] + g_b2);
  }
}

extern "C" void kernel_launch(void* const* d_in, const int* in_sizes, int n_in,
                              void* d_out, int out_size, void* d_ws, size_t ws_size,
                              hipStream_t stream) {
  const float* x    = (const float*)d_in[0];
  const int*   adjc = (const int*)  d_in[1];
  const float* ln1s = (const float*)d_in[2];
  const float* ln1b = (const float*)d_in[3];
  const float* Wq   = (const float*)d_in[4];
  const float* Wkv  = (const float*)d_in[5];
  const float* bkv  = (const float*)d_in[6];
  const float* Wout = (const float*)d_in[7];
  const float* bout = (const float*)d_in[8];
  const float* gam  = (const float*)d_in[9];
  const float* ln2s = (const float*)d_in[10];
  const float* ln2b = (const float*)d_in[11];
  const float* W1   = (const float*)d_in[12];
  const float* b1   = (const float*)d_in[13];
  const float* W2   = (const float*)d_in[14];
  const float* b2   = (const float*)d_in[15];
  const float* gmlp = (const float*)d_in[16];
  float* y = (float*)d_out;
  u16* ws = (u16*)d_ws;
  if (ws_size < WS_BYTES) return;   // deterministic guard (needs ~6.1 MB scratch)

  prep_weights<<<(WS_WTOT + 255) / 256, 256, 0, stream>>>(Wq, Wkv, Wout, W1, W2, ws + XT_ELEMS);
  ln1x_kernel<<<768, 256, 0, stream>>>(x, ln1s, ln1b, ws);
  mfa_main<<<NGRP, 256, 0, stream>>>(x, adjc, bkv, bout, gam, ln2s, ln2b,
                                     b1, b2, gmlp, ws, y);
}

// Round 5
// 155.128 us; speedup vs baseline: 1.4232x; 1.2823x over previous
//
#include <hip/hip_runtime.h>
#include <math.h>

// Dims: B=1,V=16,T=1,F=1 -> fv=16; N=12288, n=16, K=9, ATT=128, NH=4, H=32, NA=4.
// All float tensors FP32 on device. 64 tokens (16 fields x 4 nodes) per group.
//
// Swapped-operand scheme: every MFMA puts TOKEN on the B operand (n = lane&15)
// and FEATURE on A (m = 4*kgrp+r, consecutive per lane) -> all C writes are
// packed b64, softmax/LN2 reductions are in-lane + shfl_xor(16/32).
#define NNODE 12288
#define XSTRIDE 196608
#define NGRP 3072
#define XT_ELEMS 3145728        // 12288*256 bf16 LN1'd tokens [node][v][ch]
#define WS_WQT   0              // WqT[128][32]  (K-pad 16->32)
#define WS_WKVT  4096           // WkvT[256][160] (K-pad 144->160)
#define WS_WOUTT 45056          // WoutT[16][128]
#define WS_W1T   47104          // W1T[32][32]   (K-pad 16->32)
#define WS_W2T   48128          // W2T[16][32]
#define WS_WTOT  48640
#define WS_BYTES ((size_t)(XT_ELEMS + WS_WTOT) * 2)

typedef unsigned short u16;
typedef short short8 __attribute__((ext_vector_type(8)));
typedef float f32x4 __attribute__((ext_vector_type(4)));

#define MFMA16(a,b,c) __builtin_amdgcn_mfma_f32_16x16x32_bf16((a),(b),(c),0,0,0)

__device__ __forceinline__ u16 f2b(float f) {   // f32->bf16 RNE
  unsigned u = __float_as_uint(f);
  return (u16)((u + 0x7FFFu + ((u >> 16) & 1u)) >> 16);
}
__device__ __forceinline__ unsigned pk2(float a, float b) {  // 2xf32 -> packed bf16 (RTZ)
  return (__float_as_uint(a) >> 16) | (__float_as_uint(b) & 0xFFFF0000u);
}
__device__ __forceinline__ float gelu_fast(float v) {
  // 0.5 v (1+tanh(0.79788456(v+0.044715 v^3))) == v * sigmoid(1.59576912(v+0.044715v^3))
  float u = v * (1.0f + 0.044715f * v * v);
  float e = __expf(-1.5957691216057308f * u);
  return v / (1.0f + e);
}
#define DS_FENCE() do { asm volatile("s_waitcnt lgkmcnt(0)" ::: "memory"); \
                        __builtin_amdgcn_sched_barrier(0); } while (0)

// in-lane softmax over 16 values (one q-row per lane) + cross-kgrp shfl; returns 1/sum,
// overwrites s4 with exp((s-max)/sqrt(32))
__device__ __forceinline__ float softmax16(f32x4 s4[4]) {
  const float C2 = 0.25508682300212037f;  // log2(e)/sqrt(32)
  f32x4 m01, m23;
  #pragma unroll
  for (int r = 0; r < 4; ++r) { m01[r] = fmaxf(s4[0][r], s4[1][r]); m23[r] = fmaxf(s4[2][r], s4[3][r]); }
  float mx = fmaxf(fmaxf(fmaxf(m01[0], m23[0]), fmaxf(m01[1], m23[1])),
                   fmaxf(fmaxf(m01[2], m23[2]), fmaxf(m01[3], m23[3])));
  mx = fmaxf(mx, __shfl_xor(mx, 16));
  mx = fmaxf(mx, __shfl_xor(mx, 32));
  float nmx = mx * C2;
  float sum = 0.f;
  #pragma unroll
  for (int mt = 0; mt < 4; ++mt)
    #pragma unroll
    for (int r = 0; r < 4; ++r) {
      float e = exp2f(__builtin_fmaf(s4[mt][r], C2, -nmx));
      s4[mt][r] = e; sum += e;
    }
  sum += __shfl_xor(sum, 16);
  sum += __shfl_xor(sum, 32);
  return 1.0f / sum;
}

// ---------- ln1x (blocks 0..767, coalesced via LDS transpose) + weight prep (768..957) ----
__global__ __launch_bounds__(256)
void ln1x_prep(const float* __restrict__ x, const float* __restrict__ ln1s,
               const float* __restrict__ ln1b,
               const float* __restrict__ Wq, const float* __restrict__ Wkv,
               const float* __restrict__ Wout, const float* __restrict__ W1,
               const float* __restrict__ W2, u16* __restrict__ ws)
{
  const int t = threadIdx.x;
  if (blockIdx.x >= 768) {
    int i = (blockIdx.x - 768) * 256 + t;
    if (i >= WS_WTOT) return;
    u16* wbase = ws + XT_ELEMS;
    int j = i;
    if (j < 4096)  { int n = j >> 5, k = j & 31;   wbase[WS_WQT   + j] = f2b(k < 16  ? Wq[k * 128 + n]  : 0.f); return; }
    j -= 4096;
    if (j < 40960) { int n = j / 160, k = j % 160; wbase[WS_WKVT  + j] = f2b(k < 144 ? Wkv[k * 256 + n] : 0.f); return; }
    j -= 40960;
    if (j < 2048)  { int n = j >> 7, k = j & 127;  wbase[WS_WOUTT + j] = f2b(Wout[k * 16 + n]); return; }
    j -= 2048;
    if (j < 1024)  { int n = j >> 5, k = j & 31;   wbase[WS_W1T   + j] = f2b(k < 16 ? W1[k * 32 + n] : 0.f); return; }
    j -= 1024;
    { int n = j >> 5, k = j & 31; wbase[WS_W2T + j] = f2b(W2[k * 16 + n]); }
    return;
  }
  __shared__ u16 buf[4096];   // 16 nodes x 16 v x 16 ch
  const int node0 = blockIdx.x * 16;
  const int v = t >> 4, nd = t & 15;
  const f32x4* xp = (const f32x4*)(x + (size_t)v * XSTRIDE + (node0 + nd) * 16);
  f32x4 p0 = xp[0], p1 = xp[1], p2 = xp[2], p3 = xp[3];
  float va[16] = {p0[0],p0[1],p0[2],p0[3], p1[0],p1[1],p1[2],p1[3],
                  p2[0],p2[1],p2[2],p2[3], p3[0],p3[1],p3[2],p3[3]};
  float s = 0.f, ss = 0.f;
  #pragma unroll
  for (int j = 0; j < 16; ++j) { s += va[j]; ss += va[j] * va[j]; }
  float mean = s * 0.0625f, rs = rsqrtf(ss * 0.0625f - mean * mean + 1e-5f);
  short8 o0, o1;
  #pragma unroll
  for (int j = 0; j < 8; ++j) {
    o0[j] = (short)f2b((va[j]     - mean) * rs * ln1s[j]     + ln1b[j]);
    o1[j] = (short)f2b((va[j + 8] - mean) * rs * ln1s[j + 8] + ln1b[j + 8]);
  }
  *(short8*)(buf + nd * 256 + v * 16)     = o0;
  *(short8*)(buf + nd * 256 + v * 16 + 8) = o1;
  __syncthreads();
  const short8* src = (const short8*)(buf + t * 16);
  short8* dst = (short8*)(ws + node0 * 256 + t * 16);   // 16 KB contiguous per block
  dst[0] = src[0]; dst[1] = src[1];
}

// ---------- main fused kernel: one block per attention group ----------
__global__ __launch_bounds__(256, 3)
void mfa_main(const float* __restrict__ x, const int* __restrict__ adjc,
              const float* __restrict__ bkv, const float* __restrict__ bout,
              const float* __restrict__ gamma, const float* __restrict__ ln2s,
              const float* __restrict__ ln2b, const float* __restrict__ b1,
              const float* __restrict__ b2, const float* __restrict__ gmlp,
              const u16* __restrict__ ws, float* __restrict__ y)
{
  __shared__ __align__(16) unsigned char smem[49152];   // 48 KB -> 3 blocks/CU
  const int t = threadIdx.x, g = blockIdx.x;
  const int w = t >> 6, lrow = t & 15, kgrp = (t >> 4) & 3, k0 = kgrp * 8;
  const int swzl = (lrow & 7) << 4;

  char* stage = (char*)smem;                             // [64][336] gather buf
  char* kbuf  = (char*)smem;                             // after stage: k[64 tok][256B]
  char* vtb   = (char*)(smem + 16384);                   // vT[128 dim][128B]
  char* qps   = (char*)(smem + 32768 + w * 4096);        // wave slot: qp -> P -> O -> h/hid

  const u16* xt = ws;
  const u16* wb = ws + XT_ELEMS;
  const f32x4 z4 = {0.f, 0.f, 0.f, 0.f};
  const short8 z8 = {0,0,0,0,0,0,0,0};

  // ======== Phase A: stage gather + qproj (wave-local) ========
  int an[5], srow[5], scolb[5]; bool szp[5];
  #pragma unroll
  for (int p = 0; p < 5; ++p) {
    int j = p * 256 + t, s = j >> 5, half = j & 1, vv = (j & 31) >> 1;
    if (s < 36) { an[p] = adjc[g * 36 + s]; srow[p] = vv * 4 + (s / 9); scolb[p] = (s % 9) * 32 + half * 16; szp[p] = false; }
    else { srow[p] = (s - 36) * 16 + vv; scolb[p] = 288 + half * 16; szp[p] = true; an[p] = 0; }
  }
  short8 sv[5];
  #pragma unroll
  for (int p = 0; p < 5; ++p) {
    if (!szp[p]) { int j = p * 256 + t, vv = (j & 31) >> 1, half = j & 1;
                   sv[p] = *(const short8*)(xt + an[p] * 256 + vv * 16 + half * 8); }
    else sv[p] = z8;
  }
  const int tok = w * 16 + lrow, tv = tok >> 2, tnode = g * 4 + (lrow & 3);
  short8 qbx = (kgrp < 2) ? *(const short8*)(xt + tnode * 256 + tv * 16 + k0) : z8;
  #pragma unroll
  for (int p = 0; p < 5; ++p) *(short8*)(stage + srow[p] * 336 + scolb[p]) = sv[p];
  // qproj (swapped): D(m=feat 4kgrp+r, n=token lrow) -> packed b64 into qp[tok][256B]
  #pragma unroll
  for (int ft = 0; ft < 8; ++ft) {
    short8 wA = *(const short8*)(wb + WS_WQT + (ft * 16 + lrow) * 32 + k0);
    f32x4 c = MFMA16(wA, qbx, z4);
    *(uint2*)(qps + lrow * 256 + ((32 * ft + 8 * kgrp) ^ swzl)) =
        make_uint2(pk2(c[0], c[1]), pk2(c[2], c[3]));
  }
  __syncthreads();   // BAR1: stage visible

  // ======== Phase B: kvproj [64 tok][160K] -> k (swapped) + vT (orig) ========
  f32x4 acc[4][4];   // [c: 2 k-tiles + 2 v-tiles][mt: token tile]
  #pragma unroll
  for (int c = 0; c < 4; ++c)
    #pragma unroll
    for (int mt = 0; mt < 4; ++mt) acc[c][mt] = z4;
  const int ctk = 2 * w, ctv = 8 + 2 * w;
  #pragma unroll
  for (int kc = 0; kc < 5; ++kc) {
    short8 tf[4], wf[4];
    #pragma unroll
    for (int mt = 0; mt < 4; ++mt)
      tf[mt] = *(const short8*)(stage + (mt * 16 + lrow) * 336 + kc * 64 + kgrp * 16);
    wf[0] = *(const short8*)(wb + WS_WKVT + ((ctk    ) * 16 + lrow) * 160 + kc * 32 + k0);
    wf[1] = *(const short8*)(wb + WS_WKVT + ((ctk + 1) * 16 + lrow) * 160 + kc * 32 + k0);
    wf[2] = *(const short8*)(wb + WS_WKVT + ((ctv    ) * 16 + lrow) * 160 + kc * 32 + k0);
    wf[3] = *(const short8*)(wb + WS_WKVT + ((ctv + 1) * 16 + lrow) * 160 + kc * 32 + k0);
    #pragma unroll
    for (int mt = 0; mt < 4; ++mt) {
      acc[0][mt] = MFMA16(wf[0], tf[mt], acc[0][mt]);   // k: D(m=ch, n=tok)
      acc[1][mt] = MFMA16(wf[1], tf[mt], acc[1][mt]);
      acc[2][mt] = MFMA16(tf[mt], wf[2], acc[2][mt]);   // v: D(m=tok, n=ch)
      acc[3][mt] = MFMA16(tf[mt], wf[3], acc[3][mt]);
    }
  }
  __syncthreads();   // BAR2: all stage reads done before kbuf/vtb overwrite
  #pragma unroll
  for (int c = 0; c < 2; ++c) {        // k-half: pack 4 consecutive ch
    const int ct = ctk + c;
    f32x4 bk = *(const f32x4*)(bkv + ct * 16 + 4 * kgrp);
    #pragma unroll
    for (int mt = 0; mt < 4; ++mt) {
      f32x4 a = acc[c][mt];
      *(uint2*)(kbuf + (mt * 16 + lrow) * 256 + ((32 * ct + 8 * kgrp) ^ swzl)) =
          make_uint2(pk2(a[0] + bk[0], a[1] + bk[1]), pk2(a[2] + bk[2], a[3] + bk[3]));
    }
  }
  #pragma unroll
  for (int c = 0; c < 2; ++c) {        // v-half: pack 4 consecutive tokens
    const int vc = (2 * w + c) * 16 + lrow;
    float bv = bkv[128 + vc];
    #pragma unroll
    for (int mt = 0; mt < 4; ++mt) {
      f32x4 a = acc[2 + c][mt];
      *(uint2*)(vtb + vc * 128 + ((32 * mt + 8 * kgrp) ^ swzl)) =
          make_uint2(pk2(a[0] + bv, a[1] + bv), pk2(a[2] + bv, a[3] + bv));
    }
  }
  __syncthreads();   // BAR3: k/vT visible (also drains wave-local qp writes)

  // ======== Phase C: per-head S^T -> in-lane softmax -> PV (O^T), head pairs ========
  short8 qbh0 = *(const short8*)(qps + lrow * 256 + ((  0 + 16 * kgrp) ^ swzl));
  short8 qbh1 = *(const short8*)(qps + lrow * 256 + (( 64 + 16 * kgrp) ^ swzl));
  short8 qbh2 = z8, qbh3 = z8;
  f32x4 oacc[4][2];
  float invh[4];
  #pragma unroll
  for (int h = 0; h < 4; ++h) { oacc[h][0] = z4; oacc[h][1] = z4; }

  #pragma unroll
  for (int hp = 0; hp < 2; ++hp) {
    const int h0 = 2 * hp, h1 = h0 + 1;
    f32x4 s4a[4], s4b[4];
    #pragma unroll
    for (int mt = 0; mt < 4; ++mt) {
      short8 ka = *(const short8*)(kbuf + (mt * 16 + lrow) * 256 + ((64 * h0 + 16 * kgrp) ^ swzl));
      s4a[mt] = MFMA16(ka, hp ? qbh2 : qbh0, z4);   // D(m=kv, n=q=lrow)
    }
    #pragma unroll
    for (int mt = 0; mt < 4; ++mt) {
      short8 kb = *(const short8*)(kbuf + (mt * 16 + lrow) * 256 + ((64 * h1 + 16 * kgrp) ^ swzl));
      s4b[mt] = MFMA16(kb, hp ? qbh3 : qbh1, z4);
    }
    if (hp == 0) {   // prefetch Q for heads 2,3 before P overwrites qp
      qbh2 = *(const short8*)(qps + lrow * 256 + ((128 + 16 * kgrp) ^ swzl));
      qbh3 = *(const short8*)(qps + lrow * 256 + ((192 + 16 * kgrp) ^ swzl));
    }
    invh[h0] = softmax16(s4a);
    invh[h1] = softmax16(s4b);
    #pragma unroll
    for (int mt = 0; mt < 4; ++mt) {   // P (unnormalized) into qp halves, packed
      *(uint2*)(qps + lrow * 256 + ((      32 * mt + 8 * kgrp) ^ swzl)) =
          make_uint2(pk2(s4a[mt][0], s4a[mt][1]), pk2(s4a[mt][2], s4a[mt][3]));
      *(uint2*)(qps + lrow * 256 + ((128 + 32 * mt + 8 * kgrp) ^ swzl)) =
          make_uint2(pk2(s4b[mt][0], s4b[mt][1]), pk2(s4b[mt][2], s4b[mt][3]));
    }
    DS_FENCE();
    #pragma unroll
    for (int hh = 0; hh < 2; ++hh) {
      const int h = 2 * hp + hh;
      #pragma unroll
      for (int kc = 0; kc < 2; ++kc) {
        short8 pB = *(const short8*)(qps + lrow * 256 + ((128 * hh + 64 * kc + 16 * kgrp) ^ swzl));
        #pragma unroll
        for (int nt = 0; nt < 2; ++nt) {
          short8 vA = *(const short8*)(vtb + (h * 32 + nt * 16 + lrow) * 128 + ((64 * kc + 16 * kgrp) ^ swzl));
          oacc[h][nt] = MFMA16(vA, pB, oacc[h][nt]);   // O^T: D(m=dim, n=q)
        }
      }
    }
  }

  // params + residual (issued here; latency hidden under O-pack/fence)
  f32x4 p_gam = *(const f32x4*)(gamma + 4 * kgrp);
  f32x4 p_bo  = *(const f32x4*)(bout  + 4 * kgrp);
  f32x4 p_l2s = *(const f32x4*)(ln2s  + 4 * kgrp);
  f32x4 p_l2b = *(const f32x4*)(ln2b  + 4 * kgrp);
  f32x4 p_b1a = *(const f32x4*)(b1 + 4 * kgrp);
  f32x4 p_b1b = *(const f32x4*)(b1 + 16 + 4 * kgrp);
  f32x4 p_b2  = *(const f32x4*)(b2   + 4 * kgrp);
  f32x4 p_gm2 = *(const f32x4*)(gmlp + 4 * kgrp);
  f32x4 xr = *(const f32x4*)(x + (size_t)tv * XSTRIDE + tnode * 16 + 4 * kgrp);

  // O (normalized) -> qp region, packed (4 consecutive dims per write)
  #pragma unroll
  for (int h = 0; h < 4; ++h) {
    float iv = invh[h];
    #pragma unroll
    for (int nt = 0; nt < 2; ++nt) {
      f32x4 a = oacc[h][nt];
      *(uint2*)(qps + lrow * 256 + ((64 * h + 32 * nt + 8 * kgrp) ^ swzl)) =
          make_uint2(pk2(a[0] * iv, a[1] * iv), pk2(a[2] * iv, a[3] * iv));
    }
  }
  DS_FENCE();

  // ======== Phase D: outproj + LN2 + MLP (all wave-local) ========
  f32x4 oc = z4;
  #pragma unroll
  for (int kc = 0; kc < 4; ++kc) {
    short8 oB = *(const short8*)(qps + lrow * 256 + ((64 * kc + 16 * kgrp) ^ swzl));
    short8 wo = *(const short8*)(wb + WS_WOUTT + lrow * 128 + kc * 32 + k0);
    oc = MFMA16(wo, oB, oc);   // D(m=ch 4kgrp+r, n=token lrow)
  }
  float xov[4]; float s = 0.f, ss = 0.f;
  #pragma unroll
  for (int r = 0; r < 4; ++r) {
    xov[r] = xr[r] + p_gam[r] * (oc[r] + p_bo[r]);
    s += xov[r]; ss += xov[r] * xov[r];
  }
  s  += __shfl_xor(s, 16);  s  += __shfl_xor(s, 32);
  ss += __shfl_xor(ss, 16); ss += __shfl_xor(ss, 32);
  float mean = s * 0.0625f, rstd = rsqrtf(ss * 0.0625f - mean * mean + 1e-5f);
  float hv[4];
  #pragma unroll
  for (int r = 0; r < 4; ++r) hv[r] = (xov[r] - mean) * rstd * p_l2s[r] + p_l2b[r];
  *(uint2*)(qps + lrow * 64 + 8 * kgrp)      = make_uint2(pk2(hv[0], hv[1]), pk2(hv[2], hv[3]));
  *(uint2*)(qps + lrow * 64 + 32 + 8 * kgrp) = make_uint2(0u, 0u);   // K-pad 16..31
  DS_FENCE();
  short8 hB = *(const short8*)(qps + lrow * 64 + 16 * kgrp);
  float hid[8];
  #pragma unroll
  for (int ft = 0; ft < 2; ++ft) {
    short8 w1 = *(const short8*)(wb + WS_W1T + (ft * 16 + lrow) * 32 + k0);
    f32x4 hc = MFMA16(w1, hB, z4);    // D(m=hch, n=token)
    f32x4 bb = ft ? p_b1b : p_b1a;
    #pragma unroll
    for (int r = 0; r < 4; ++r) hid[ft * 4 + r] = gelu_fast(hc[r] + bb[r]);
  }
  *(uint2*)(qps + 2048 + lrow * 64 + 8 * kgrp)      = make_uint2(pk2(hid[0], hid[1]), pk2(hid[2], hid[3]));
  *(uint2*)(qps + 2048 + lrow * 64 + 32 + 8 * kgrp) = make_uint2(pk2(hid[4], hid[5]), pk2(hid[6], hid[7]));
  DS_FENCE();
  short8 hidB = *(const short8*)(qps + 2048 + lrow * 64 + 16 * kgrp);
  short8 w2 = *(const short8*)(wb + WS_W2T + lrow * 32 + k0);
  f32x4 mc = MFMA16(w2, hidB, z4);    // D(m=out-ch 4kgrp+r, n=token lrow)
  f32x4 yv;
  #pragma unroll
  for (int r = 0; r < 4; ++r) yv[r] = xov[r] + p_gm2[r] * (mc[r] + p_b2[r]);
  *(f32x4*)(y + (size_t)tv * XSTRIDE + tnode * 16 + 4 * kgrp) = yv;
}

extern "C" void kernel_launch(void* const* d_in, const int* in_sizes, int n_in,
                              void* d_out, int out_size, void* d_ws, size_t ws_size,
                              hipStream_t stream) {
  const float* x    = (const float*)d_in[0];
  const int*   adjc = (const int*)  d_in[1];
  const float* ln1s = (const float*)d_in[2];
  const float* ln1b = (const float*)d_in[3];
  const float* Wq   = (const float*)d_in[4];
  const float* Wkv  = (const float*)d_in[5];
  const float* bkv  = (const float*)d_in[6];
  const float* Wout = (const float*)d_in[7];
  const float* bout = (const float*)d_in[8];
  const float* gam  = (const float*)d_in[9];
  const float* ln2s = (const float*)d_in[10];
  const float* ln2b = (const float*)d_in[11];
  const float* W1   = (const float*)d_in[12];
  const float* b1   = (const float*)d_in[13];
  const float* W2   = (const float*)d_in[14];
  const float* b2   = (const float*)d_in[15];
  const float* gmlp = (const float*)d_in[16];
  float* y = (float*)d_out;
  u16* ws = (u16*)d_ws;
  if (ws_size < WS_BYTES) return;   // needs ~6.4 MB scratch

  ln1x_prep<<<958, 256, 0, stream>>>(x, ln1s, ln1b, Wq, Wkv, Wout, W1, W2, ws);
  mfa_main<<<NGRP, 256, 0, stream>>>(x, adjc, bkv, bout, gam, ln2s, ln2b,
                                     b1, b2, gmlp, ws, y);
}